// Round 9
// baseline (217.524 us; speedup 1.0000x reference)
//
#include <hip/hip_runtime.h>
#include <hip/hip_bf16.h>

#define BB 8
#define FF 4096
#define SS 1024
#define DD 128
#define DLL 256
#define NF (BB*FF)     // 32768 facts
#define NMSG (2*NF)    // 65536 message slots
#define NNODE (BB*SS)  // 8192 (b,s) rows
#define FPB 32         // facts per msg block (64 messages)
#define CAP 36         // bucket capacity per node

typedef short  short8 __attribute__((ext_vector_type(8)));
typedef float  f32x4  __attribute__((ext_vector_type(4)));

__device__ __forceinline__ uint f2bf(float x) {
    uint u = __float_as_uint(x);
    return (u + 0x7fffu + ((u >> 16) & 1u)) >> 16;
}
__device__ __forceinline__ float bf2f(uint lo16) {
    return __uint_as_float(lo16 << 16);
}

// gelu(x) = 0.5x(1+erf(x/sqrt2)); erf via A&S 7.1.26, |err|<=1.5e-7, branchless.
__device__ __forceinline__ float gelu_fast(float x) {
    const float z = fabsf(x) * 0.70710678118654752440f;
    const float t = __builtin_amdgcn_rcpf(__builtin_fmaf(0.3275911f, z, 1.0f));
    float p = 1.061405429f;
    p = __builtin_fmaf(p, t, -1.453152027f);
    p = __builtin_fmaf(p, t, 1.421413741f);
    p = __builtin_fmaf(p, t, -0.284496736f);
    p = __builtin_fmaf(p, t, 0.254829592f);
    p *= t;
    const float e = __expf(-z * z);
    const float erfv = __builtin_fmaf(-p, e, 1.0f);
    return 0.5f * x * (1.0f + copysignf(erfv, x));
}

// ---------------------------------------------------------------------------
// Prep: table GEMMs Pa/Pc/PE (fp32 math, bf16 store), w2 frag-pack, zeroing.
//   Pa[s][j] = sum_k pos[s][k] w1[k][j]          (k = 0..128)
//   Pc[s][j] = sum_k pos[s][k] w1[256+k][j]
//   PE[r][j] = sum_k pred[r][k] w1[128+k][j] + b1[j]
// ---------------------------------------------------------------------------
#define N_W2 (256*128)
#define PA_BLOCKS 128                      // 8 s-rows per block
#define PE_BLOCK  PA_BLOCKS
#define FLAT0     (PA_BLOCKS + 1)
#define N_FLAT    (N_W2 + NNODE + BB*DD + 1)
#define FLAT_BLOCKS ((N_FLAT + 255) / 256)
#define PREP_GRID (FLAT0 + FLAT_BLOCKS)

__global__ __launch_bounds__(256) void prep_kernel(
    const float* __restrict__ pos_emb, const float* __restrict__ pred_emb,
    const float* __restrict__ w1, const float* __restrict__ b1,
    const float* __restrict__ w2,
    ushort* __restrict__ Pa, ushort* __restrict__ Pc, ushort* __restrict__ PE,
    ushort* __restrict__ w2p, int* __restrict__ cnt,
    float* __restrict__ pooled, int* __restrict__ done)
{
    const int blk = blockIdx.x;
    const int tid = threadIdx.x;

    if (blk < PA_BLOCKS) {
        __shared__ float ps[8][128];
        const int s0 = blk * 8;
        for (int q = tid; q < 1024; q += 256) ps[q >> 7][q & 127] = pos_emb[s0 * 128 + q];
        __syncthreads();
        const int j = tid;
        float aa[8], ac[8];
        #pragma unroll
        for (int r = 0; r < 8; ++r) { aa[r] = 0.0f; ac[r] = 0.0f; }
        for (int k = 0; k < 128; ++k) {
            const float wa = w1[k * 256 + j];
            const float wc = w1[(256 + k) * 256 + j];
            #pragma unroll
            for (int r = 0; r < 8; ++r) {
                aa[r] = __builtin_fmaf(ps[r][k], wa, aa[r]);
                ac[r] = __builtin_fmaf(ps[r][k], wc, ac[r]);
            }
        }
        #pragma unroll
        for (int r = 0; r < 8; ++r) {
            Pa[(s0 + r) * 256 + j] = (ushort)f2bf(aa[r]);
            Pc[(s0 + r) * 256 + j] = (ushort)f2bf(ac[r]);
        }
        return;
    }
    if (blk == PE_BLOCK) {
        __shared__ float pr[14][128];
        for (int q = tid; q < 14 * 128; q += 256) pr[q >> 7][q & 127] = pred_emb[q];
        __syncthreads();
        const int j = tid;
        float acc[14];
        #pragma unroll
        for (int r = 0; r < 14; ++r) acc[r] = 0.0f;
        for (int k = 0; k < 128; ++k) {
            const float wb = w1[(128 + k) * 256 + j];
            #pragma unroll
            for (int r = 0; r < 14; ++r) acc[r] = __builtin_fmaf(pr[r][k], wb, acc[r]);
        }
        const float bj = b1[j];
        #pragma unroll
        for (int r = 0; r < 14; ++r) PE[r * 256 + j] = (ushort)f2bf(acc[r] + bj);
        return;
    }
    int i = (blk - FLAT0) * 256 + tid;
    if (i < N_W2) {   // i = k*128 + d -> frag-packed for GEMM2 A operand
        const int k = i >> 7, d = i & 127;
        const int d0 = d >> 4, lr = d & 15, ks = k >> 5, lq = (k >> 3) & 3, e = k & 7;
        w2p[(d0 * 8 + ks) * 512 + lr * 32 + lq * 8 + e] = (ushort)f2bf(w2[i]);
        return;
    }
    i -= N_W2;
    if (i < NNODE) { cnt[i] = 0; return; }
    i -= NNODE;
    if (i < BB * DD) { pooled[i] = 0.0f; return; }
    i -= BB * DD;
    if (i == 0) *done = 0;
}

// ---------------------------------------------------------------------------
// msg kernel: table-gather + gelu -> swizzled LDS h1 -> GEMM2 (MFMA) -> stores.
// 32 facts / 64 messages per block, 4 waves; wave w computes msgs w*16..+16.
// Also builds node->msg bucket index (first 64 threads).
// ---------------------------------------------------------------------------
__global__ __launch_bounds__(256, 4) void msg_kernel(
    const int* __restrict__ a0, const int* __restrict__ a1,
    const int* __restrict__ pidx, const float* __restrict__ bidir,
    const ushort* __restrict__ Pa, const ushort* __restrict__ Pc,
    const ushort* __restrict__ PE,
    const ushort* __restrict__ w2p, const float* __restrict__ b2,
    ushort* __restrict__ msgbuf, int* __restrict__ cnt, ushort* __restrict__ idx16)
{
    __shared__ uint4 shm[2048];           // 32 KB: h1g[64 rows][512 B], swizzled

    const int tid = threadIdx.x;
    const int fbase = blockIdx.x * FPB;
    const int wid = tid >> 6, lane = tid & 63;
    const int lq = lane >> 4, lr = lane & 15;
    const int factL = lr >> 1, par = lr & 1;

    // ---- bucket build: one thread per message of this block ----
    if (tid < 2 * FPB) {
        const int i = blockIdx.x * (2 * FPB) + tid;
        const int g = i >> 1, p = i & 1;
        const float w = p ? bidir[g] : 1.0f;
        if (w != 0.0f) {
            const int nid = ((g >> 12) << 10) + (p ? a0[g] : a1[g]);
            const int slot = atomicAdd(&cnt[nid], 1);
            if (slot < CAP) idx16[nid * CAP + slot] = (ushort)i;
        }
    }

    // ---- phase A: h1 = Pa[X] + PE[pi] + Pc[Y]; gelu; bf16 -> LDS ----
    #pragma unroll 4
    for (int i = 0; i < 16; ++i) {
        const int m = wid * 16 + i;
        const int f = fbase + (m >> 1);
        const int p = m & 1;
        const int ra0 = a0[f], ra1 = a1[f], rpi = pidx[f];
        const int X = p ? ra1 : ra0;     // through W1a
        const int Y = p ? ra0 : ra1;     // through W1c
        const uint2 ua = *(const uint2*)(Pa + X * 256 + lane * 4);
        const uint2 ub = *(const uint2*)(PE + rpi * 256 + lane * 4);
        const uint2 uc = *(const uint2*)(Pc + Y * 256 + lane * 4);
        const float h0 = bf2f(ua.x & 0xffffu) + bf2f(ub.x & 0xffffu) + bf2f(uc.x & 0xffffu);
        const float h1 = bf2f(ua.x >> 16)     + bf2f(ub.x >> 16)     + bf2f(uc.x >> 16);
        const float h2 = bf2f(ua.y & 0xffffu) + bf2f(ub.y & 0xffffu) + bf2f(uc.y & 0xffffu);
        const float h3 = bf2f(ua.y >> 16)     + bf2f(ub.y >> 16)     + bf2f(uc.y >> 16);
        uint2 t;
        t.x = f2bf(gelu_fast(h0)) | (f2bf(gelu_fast(h1)) << 16);
        t.y = f2bf(gelu_fast(h2)) | (f2bf(gelu_fast(h3)) << 16);
        const int col = lane * 8;     // byte col within 512B row
        const int byteoff = m * 512 + ((((col >> 4)) ^ (m & 15)) << 4) + (col & 15);
        *(uint2*)((char*)shm + byteoff) = t;
    }
    __syncthreads();

    // ---- GEMM2: D2[d][m], acc2[nf][mf]; d = wid*32+nf*16+(lq*4+r), m=mf*16+lr ----
    f32x4 acc2[2][4];
    #pragma unroll
    for (int nf = 0; nf < 2; ++nf)
        #pragma unroll
        for (int mf = 0; mf < 4; ++mf) acc2[nf][mf] = (f32x4)0.0f;

    #pragma unroll
    for (int ks = 0; ks < 8; ++ks) {
        short8 hfrag[4];
        #pragma unroll
        for (int mf = 0; mf < 4; ++mf) {
            const int m = mf * 16 + lr;
            hfrag[mf] = *(const short8*)((char*)shm + m * 512 + ((((ks * 4 + lq)) ^ (m & 15)) << 4));
        }
        short8 w2frag[2];
        #pragma unroll
        for (int nf = 0; nf < 2; ++nf)
            w2frag[nf] = *(const short8*)(w2p + ((wid * 2 + nf) * 8 + ks) * 512 + lr * 32 + lq * 8);
        #pragma unroll
        for (int nf = 0; nf < 2; ++nf)
            #pragma unroll
            for (int mf = 0; mf < 4; ++mf)
                acc2[nf][mf] = __builtin_amdgcn_mfma_f32_16x16x32_bf16(w2frag[nf], hfrag[mf], acc2[nf][mf], 0, 0, 0);
    }

    // ---- epilogue: bias + bidir weight + plain bf16 stores (8B/lane) ----
    {
        float wgt_[4];
        #pragma unroll
        for (int mf = 0; mf < 4; ++mf) {
            const int g = fbase + mf * 8 + factL;
            wgt_[mf] = par ? bidir[g] : 1.0f;
        }
        #pragma unroll
        for (int nf = 0; nf < 2; ++nf) {
            const float4 bd = *(const float4*)(b2 + wid * 32 + nf * 16 + lq * 4);
            const int d0 = wid * 32 + nf * 16 + lq * 4;
            #pragma unroll
            for (int mf = 0; mf < 4; ++mf) {
                const int m = mf * 16 + lr;
                const float w = wgt_[mf];
                if (w != 0.0f) {
                    uint2 t;
                    t.x = f2bf((acc2[nf][mf][0] + bd.x) * w) |
                          (f2bf((acc2[nf][mf][1] + bd.y) * w) << 16);
                    t.y = f2bf((acc2[nf][mf][2] + bd.z) * w) |
                          (f2bf((acc2[nf][mf][3] + bd.w) * w) << 16);
                    *(uint2*)(msgbuf + (size_t)(fbase * 2 + m) * DD + d0) = t;
                }
            }
        }
    }
}

// ---------------------------------------------------------------------------
// Fused bucket-gather + LayerNorm + pool; last block runs the latent head.
// ---------------------------------------------------------------------------
__global__ __launch_bounds__(256) void reduce_kernel(
    const float* __restrict__ pos_emb, const ushort* __restrict__ msgbuf,
    const int* __restrict__ cnt, const ushort* __restrict__ idx16,
    const float* __restrict__ ln_g, const float* __restrict__ ln_b,
    float* __restrict__ pooled, int* __restrict__ done,
    const float* __restrict__ lw1, const float* __restrict__ lb1,
    const float* __restrict__ lw2, const float* __restrict__ lb2,
    float* __restrict__ out)
{
    const int wave = threadIdx.x >> 6, lane = threadIdx.x & 63;
    const int nid = blockIdx.x * 4 + wave;
    const int s = nid & (SS - 1);
    const int b = (blockIdx.x * 4) >> 10;

    float2 h = *(const float2*)(pos_emb + s * DD + 2 * lane);
    int c = cnt[nid]; if (c > CAP) c = CAP;
    const ushort* bucket = idx16 + nid * CAP;
    for (int j = 0; j < c; ++j) {
        const uint mid = bucket[j];
        const uint u = *(const uint*)(msgbuf + (size_t)mid * DD + 2 * lane);
        h.x += bf2f(u & 0xffffu);
        h.y += bf2f(u >> 16);
    }

    float sum = h.x + h.y;
    #pragma unroll
    for (int o = 32; o > 0; o >>= 1) sum += __shfl_xor(sum, o);
    const float mu = sum * (1.0f / 128.0f);
    const float d0 = h.x - mu, d1 = h.y - mu;
    float sq = d0 * d0 + d1 * d1;
    #pragma unroll
    for (int o = 32; o > 0; o >>= 1) sq += __shfl_xor(sq, o);
    const float rstd = rsqrtf(sq * (1.0f / 128.0f) + 1e-5f);

    const float2 g2  = *(const float2*)(ln_g + 2 * lane);
    const float2 bb2 = *(const float2*)(ln_b + 2 * lane);
    const float p0 = d0 * rstd * g2.x + bb2.x;
    const float p1 = d1 * rstd * g2.y + bb2.y;

    __shared__ float red[4][128];
    red[wave][2 * lane]     = p0;
    red[wave][2 * lane + 1] = p1;
    __syncthreads();
    if (threadIdx.x < 128) {
        const float v = red[0][threadIdx.x] + red[1][threadIdx.x]
                      + red[2][threadIdx.x] + red[3][threadIdx.x];
        atomicAdd(&pooled[b * DD + threadIdx.x], v);
    }

    // ---- last block runs the head ----
    __threadfence();
    __shared__ int islast;
    if (threadIdx.x == 0) islast = (atomicAdd(done, 1) == (NNODE / 4) - 1) ? 1 : 0;
    __syncthreads();
    if (!islast) return;
    __threadfence();

    __shared__ float p[128];
    __shared__ float t1[256];
    const int j = threadIdx.x;
    for (int bb = 0; bb < BB; ++bb) {
        if (j < 128) p[j] = pooled[bb * DD + j] * (1.0f / (float)SS);
        __syncthreads();
        float acc = lb1[j];
        for (int k = 0; k < 128; ++k) acc = __builtin_fmaf(p[k], lw1[k * 256 + j], acc);
        t1[j] = gelu_fast(acc);
        __syncthreads();
        float acc2 = lb2[j];
        for (int k = 0; k < 256; ++k) acc2 = __builtin_fmaf(t1[k], lw2[k * 256 + j], acc2);
        out[bb * DLL + j] = acc2;
        __syncthreads();
    }
}

extern "C" void kernel_launch(void* const* d_in, const int* in_sizes, int n_in,
                              void* d_out, int out_size, void* d_ws, size_t ws_size,
                              hipStream_t stream) {
    const int*   a0       = (const int*)d_in[0];
    const int*   a1       = (const int*)d_in[1];
    const int*   pidx     = (const int*)d_in[2];
    const float* bidir    = (const float*)d_in[3];
    const float* pos_emb  = (const float*)d_in[4];
    const float* pred_emb = (const float*)d_in[5];
    const float* w1       = (const float*)d_in[6];
    const float* b1       = (const float*)d_in[7];
    const float* w2       = (const float*)d_in[8];
    const float* b2       = (const float*)d_in[9];
    const float* ln_g     = (const float*)d_in[10];
    const float* ln_b     = (const float*)d_in[11];
    const float* lw1      = (const float*)d_in[12];
    const float* lb1      = (const float*)d_in[13];
    const float* lw2      = (const float*)d_in[14];
    const float* lb2      = (const float*)d_in[15];

    char* ws = (char*)d_ws;   // ws_size = 256 MB (observed via harness poison fill)
    const size_t O_MSG  = 0;                               // 16 MB
    const size_t O_CNT  = 16777216;                        // 32 KB
    const size_t O_POOL = O_CNT + 32768;                   // 4 KB
    const size_t O_DONE = O_POOL + 4096;                   // 256 B
    const size_t O_IDX  = O_DONE + 256;                    // 576 KB
    const size_t O_W2P  = O_IDX + (size_t)NNODE * CAP * 2; // 64 KB
    const size_t O_PA   = O_W2P + 65536;                   // 512 KB
    const size_t O_PC   = O_PA + 524288;                   // 512 KB
    const size_t O_PE   = O_PC + 524288;                   // 7 KB

    ushort* msgbuf = (ushort*)(ws + O_MSG);
    int*    cnt    = (int*)(ws + O_CNT);
    float*  pooled = (float*)(ws + O_POOL);
    int*    done   = (int*)(ws + O_DONE);
    ushort* idx16  = (ushort*)(ws + O_IDX);
    ushort* w2p    = (ushort*)(ws + O_W2P);
    ushort* Pa     = (ushort*)(ws + O_PA);
    ushort* Pc     = (ushort*)(ws + O_PC);
    ushort* PE     = (ushort*)(ws + O_PE);

    prep_kernel<<<PREP_GRID, 256, 0, stream>>>(
        pos_emb, pred_emb, w1, b1, w2, Pa, Pc, PE, w2p, cnt, pooled, done);
    msg_kernel<<<NF / FPB, 256, 0, stream>>>(a0, a1, pidx, bidir,
        Pa, Pc, PE, w2p, b2, msgbuf, cnt, idx16);
    reduce_kernel<<<NNODE / 4, 256, 0, stream>>>(
        pos_emb, msgbuf, cnt, idx16, ln_g, ln_b, pooled, done,
        lw1, lb1, lw2, lb2, (float*)d_out);
}

// Round 10
// 65.992 us; speedup vs baseline: 3.2962x; 3.2962x over previous
//
#include <hip/hip_runtime.h>
#include <hip/hip_bf16.h>

#define BB 8
#define FF 4096
#define SS 1024
#define DD 128
#define DLL 256
#define NF (BB*FF)     // 32768 facts
#define NMSG (2*NF)    // 65536 message slots
#define NNODE (BB*SS)  // 8192 (b,s) rows
#define FPB 32         // facts per msg block (64 messages)
#define CAP 36         // bucket capacity per node

typedef short  short8 __attribute__((ext_vector_type(8)));
typedef float  f32x4  __attribute__((ext_vector_type(4)));

__device__ __forceinline__ uint f2bf(float x) {
    uint u = __float_as_uint(x);
    return (u + 0x7fffu + ((u >> 16) & 1u)) >> 16;
}
__device__ __forceinline__ float bf2f(uint lo16) {
    return __uint_as_float(lo16 << 16);
}

// gelu(x) = 0.5x(1+erf(x/sqrt2)); erf via A&S 7.1.26, |err|<=1.5e-7, branchless.
__device__ __forceinline__ float gelu_fast(float x) {
    const float z = fabsf(x) * 0.70710678118654752440f;
    const float t = __builtin_amdgcn_rcpf(__builtin_fmaf(0.3275911f, z, 1.0f));
    float p = 1.061405429f;
    p = __builtin_fmaf(p, t, -1.453152027f);
    p = __builtin_fmaf(p, t, 1.421413741f);
    p = __builtin_fmaf(p, t, -0.284496736f);
    p = __builtin_fmaf(p, t, 0.254829592f);
    p *= t;
    const float e = __expf(-z * z);
    const float erfv = __builtin_fmaf(-p, e, 1.0f);
    return 0.5f * x * (1.0f + copysignf(erfv, x));
}

// ---------------------------------------------------------------------------
// Prep: table GEMMs Pa/Pc/PE (fp32 math, bf16 store), w2 frag-pack, zeroing.
//   Pa[s][j] = sum_k pos[s][k] w1[k][j]          (k = 0..128)
//   Pc[s][j] = sum_k pos[s][k] w1[256+k][j]
//   PE[r][j] = sum_k pred[r][k] w1[128+k][j] + b1[j]
// ---------------------------------------------------------------------------
#define N_W2 (256*128)
#define PA_BLOCKS 128                      // 8 s-rows per block
#define PE_BLOCK  PA_BLOCKS
#define FLAT0     (PA_BLOCKS + 1)
#define N_FLAT    (N_W2 + NNODE + BB*DD)
#define FLAT_BLOCKS ((N_FLAT + 255) / 256)
#define PREP_GRID (FLAT0 + FLAT_BLOCKS)

__global__ __launch_bounds__(256) void prep_kernel(
    const float* __restrict__ pos_emb, const float* __restrict__ pred_emb,
    const float* __restrict__ w1, const float* __restrict__ b1,
    const float* __restrict__ w2,
    ushort* __restrict__ Pa, ushort* __restrict__ Pc, ushort* __restrict__ PE,
    ushort* __restrict__ w2p, int* __restrict__ cnt,
    float* __restrict__ pooled)
{
    const int blk = blockIdx.x;
    const int tid = threadIdx.x;

    if (blk < PA_BLOCKS) {
        __shared__ float ps[8][128];
        const int s0 = blk * 8;
        for (int q = tid; q < 1024; q += 256) ps[q >> 7][q & 127] = pos_emb[s0 * 128 + q];
        __syncthreads();
        const int j = tid;
        float aa[8], ac[8];
        #pragma unroll
        for (int r = 0; r < 8; ++r) { aa[r] = 0.0f; ac[r] = 0.0f; }
        for (int k = 0; k < 128; ++k) {
            const float wa = w1[k * 256 + j];
            const float wc = w1[(256 + k) * 256 + j];
            #pragma unroll
            for (int r = 0; r < 8; ++r) {
                aa[r] = __builtin_fmaf(ps[r][k], wa, aa[r]);
                ac[r] = __builtin_fmaf(ps[r][k], wc, ac[r]);
            }
        }
        #pragma unroll
        for (int r = 0; r < 8; ++r) {
            Pa[(s0 + r) * 256 + j] = (ushort)f2bf(aa[r]);
            Pc[(s0 + r) * 256 + j] = (ushort)f2bf(ac[r]);
        }
        return;
    }
    if (blk == PE_BLOCK) {
        __shared__ float pr[14][128];
        for (int q = tid; q < 14 * 128; q += 256) pr[q >> 7][q & 127] = pred_emb[q];
        __syncthreads();
        const int j = tid;
        float acc[14];
        #pragma unroll
        for (int r = 0; r < 14; ++r) acc[r] = 0.0f;
        for (int k = 0; k < 128; ++k) {
            const float wb = w1[(128 + k) * 256 + j];
            #pragma unroll
            for (int r = 0; r < 14; ++r) acc[r] = __builtin_fmaf(pr[r][k], wb, acc[r]);
        }
        const float bj = b1[j];
        #pragma unroll
        for (int r = 0; r < 14; ++r) PE[r * 256 + j] = (ushort)f2bf(acc[r] + bj);
        return;
    }
    int i = (blk - FLAT0) * 256 + tid;
    if (i < N_W2) {   // i = k*128 + d -> frag-packed for GEMM2 A operand
        const int k = i >> 7, d = i & 127;
        const int d0 = d >> 4, lr = d & 15, ks = k >> 5, lq = (k >> 3) & 3, e = k & 7;
        w2p[(d0 * 8 + ks) * 512 + lr * 32 + lq * 8 + e] = (ushort)f2bf(w2[i]);
        return;
    }
    i -= N_W2;
    if (i < NNODE) { cnt[i] = 0; return; }
    i -= NNODE;
    if (i < BB * DD) pooled[i] = 0.0f;
}

// ---------------------------------------------------------------------------
// msg kernel: table-gather + gelu -> swizzled LDS h1 -> GEMM2 (MFMA) -> stores.
// 32 facts / 64 messages per block, 4 waves; wave w computes msgs w*16..+16.
// Also builds node->msg bucket index (first 64 threads).
// ---------------------------------------------------------------------------
__global__ __launch_bounds__(256, 4) void msg_kernel(
    const int* __restrict__ a0, const int* __restrict__ a1,
    const int* __restrict__ pidx, const float* __restrict__ bidir,
    const ushort* __restrict__ Pa, const ushort* __restrict__ Pc,
    const ushort* __restrict__ PE,
    const ushort* __restrict__ w2p, const float* __restrict__ b2,
    ushort* __restrict__ msgbuf, int* __restrict__ cnt, ushort* __restrict__ idx16)
{
    __shared__ uint4 shm[2048];           // 32 KB: h1g[64 rows][512 B], swizzled

    const int tid = threadIdx.x;
    const int fbase = blockIdx.x * FPB;
    const int wid = tid >> 6, lane = tid & 63;
    const int lq = lane >> 4, lr = lane & 15;
    const int factL = lr >> 1, par = lr & 1;

    // ---- bucket build: one thread per message of this block ----
    if (tid < 2 * FPB) {
        const int i = blockIdx.x * (2 * FPB) + tid;
        const int g = i >> 1, p = i & 1;
        const float w = p ? bidir[g] : 1.0f;
        if (w != 0.0f) {
            const int nid = ((g >> 12) << 10) + (p ? a0[g] : a1[g]);
            const int slot = atomicAdd(&cnt[nid], 1);
            if (slot < CAP) idx16[nid * CAP + slot] = (ushort)i;
        }
    }

    // ---- phase A: h1 = Pa[X] + PE[pi] + Pc[Y]; gelu; bf16 -> LDS ----
    #pragma unroll 4
    for (int i = 0; i < 16; ++i) {
        const int m = wid * 16 + i;
        const int f = fbase + (m >> 1);
        const int p = m & 1;
        const int ra0 = a0[f], ra1 = a1[f], rpi = pidx[f];
        const int X = p ? ra1 : ra0;     // through W1a
        const int Y = p ? ra0 : ra1;     // through W1c
        const uint2 ua = *(const uint2*)(Pa + X * 256 + lane * 4);
        const uint2 ub = *(const uint2*)(PE + rpi * 256 + lane * 4);
        const uint2 uc = *(const uint2*)(Pc + Y * 256 + lane * 4);
        const float h0 = bf2f(ua.x & 0xffffu) + bf2f(ub.x & 0xffffu) + bf2f(uc.x & 0xffffu);
        const float h1 = bf2f(ua.x >> 16)     + bf2f(ub.x >> 16)     + bf2f(uc.x >> 16);
        const float h2 = bf2f(ua.y & 0xffffu) + bf2f(ub.y & 0xffffu) + bf2f(uc.y & 0xffffu);
        const float h3 = bf2f(ua.y >> 16)     + bf2f(ub.y >> 16)     + bf2f(uc.y >> 16);
        uint2 t;
        t.x = f2bf(gelu_fast(h0)) | (f2bf(gelu_fast(h1)) << 16);
        t.y = f2bf(gelu_fast(h2)) | (f2bf(gelu_fast(h3)) << 16);
        const int col = lane * 8;     // byte col within 512B row
        const int byteoff = m * 512 + ((((col >> 4)) ^ (m & 15)) << 4) + (col & 15);
        *(uint2*)((char*)shm + byteoff) = t;
    }
    __syncthreads();

    // ---- GEMM2: D2[d][m], acc2[nf][mf]; d = wid*32+nf*16+(lq*4+r), m=mf*16+lr ----
    f32x4 acc2[2][4];
    #pragma unroll
    for (int nf = 0; nf < 2; ++nf)
        #pragma unroll
        for (int mf = 0; mf < 4; ++mf) acc2[nf][mf] = (f32x4)0.0f;

    #pragma unroll
    for (int ks = 0; ks < 8; ++ks) {
        short8 hfrag[4];
        #pragma unroll
        for (int mf = 0; mf < 4; ++mf) {
            const int m = mf * 16 + lr;
            hfrag[mf] = *(const short8*)((char*)shm + m * 512 + ((((ks * 4 + lq)) ^ (m & 15)) << 4));
        }
        short8 w2frag[2];
        #pragma unroll
        for (int nf = 0; nf < 2; ++nf)
            w2frag[nf] = *(const short8*)(w2p + ((wid * 2 + nf) * 8 + ks) * 512 + lr * 32 + lq * 8);
        #pragma unroll
        for (int nf = 0; nf < 2; ++nf)
            #pragma unroll
            for (int mf = 0; mf < 4; ++mf)
                acc2[nf][mf] = __builtin_amdgcn_mfma_f32_16x16x32_bf16(w2frag[nf], hfrag[mf], acc2[nf][mf], 0, 0, 0);
    }

    // ---- epilogue: bias + bidir weight + plain bf16 stores (8B/lane) ----
    {
        float wgt_[4];
        #pragma unroll
        for (int mf = 0; mf < 4; ++mf) {
            const int g = fbase + mf * 8 + factL;
            wgt_[mf] = par ? bidir[g] : 1.0f;
        }
        #pragma unroll
        for (int nf = 0; nf < 2; ++nf) {
            const float4 bd = *(const float4*)(b2 + wid * 32 + nf * 16 + lq * 4);
            const int d0 = wid * 32 + nf * 16 + lq * 4;
            #pragma unroll
            for (int mf = 0; mf < 4; ++mf) {
                const int m = mf * 16 + lr;
                const float w = wgt_[mf];
                if (w != 0.0f) {
                    uint2 t;
                    t.x = f2bf((acc2[nf][mf][0] + bd.x) * w) |
                          (f2bf((acc2[nf][mf][1] + bd.y) * w) << 16);
                    t.y = f2bf((acc2[nf][mf][2] + bd.z) * w) |
                          (f2bf((acc2[nf][mf][3] + bd.w) * w) << 16);
                    *(uint2*)(msgbuf + (size_t)(fbase * 2 + m) * DD + d0) = t;
                }
            }
        }
    }
}

// ---------------------------------------------------------------------------
// Fused bucket-gather + LayerNorm + pool.  One wave per node, 4 nodes/block.
// ---------------------------------------------------------------------------
__global__ __launch_bounds__(256) void reduce_kernel(
    const float* __restrict__ pos_emb, const ushort* __restrict__ msgbuf,
    const int* __restrict__ cnt, const ushort* __restrict__ idx16,
    const float* __restrict__ ln_g, const float* __restrict__ ln_b,
    float* __restrict__ pooled)
{
    const int wave = threadIdx.x >> 6, lane = threadIdx.x & 63;
    const int nid = blockIdx.x * 4 + wave;
    const int s = nid & (SS - 1);
    const int b = (blockIdx.x * 4) >> 10;

    float2 h = *(const float2*)(pos_emb + s * DD + 2 * lane);
    int c = cnt[nid]; if (c > CAP) c = CAP;
    const ushort* bucket = idx16 + nid * CAP;
    for (int j = 0; j < c; ++j) {
        const uint mid = bucket[j];
        const uint u = *(const uint*)(msgbuf + (size_t)mid * DD + 2 * lane);
        h.x += bf2f(u & 0xffffu);
        h.y += bf2f(u >> 16);
    }

    float sum = h.x + h.y;
    #pragma unroll
    for (int o = 32; o > 0; o >>= 1) sum += __shfl_xor(sum, o);
    const float mu = sum * (1.0f / 128.0f);
    const float d0 = h.x - mu, d1 = h.y - mu;
    float sq = d0 * d0 + d1 * d1;
    #pragma unroll
    for (int o = 32; o > 0; o >>= 1) sq += __shfl_xor(sq, o);
    const float rstd = rsqrtf(sq * (1.0f / 128.0f) + 1e-5f);

    const float2 g2  = *(const float2*)(ln_g + 2 * lane);
    const float2 bb2 = *(const float2*)(ln_b + 2 * lane);
    const float p0 = d0 * rstd * g2.x + bb2.x;
    const float p1 = d1 * rstd * g2.y + bb2.y;

    __shared__ float red[4][128];
    red[wave][2 * lane]     = p0;
    red[wave][2 * lane + 1] = p1;
    __syncthreads();
    if (threadIdx.x < 128) {
        const float v = red[0][threadIdx.x] + red[1][threadIdx.x]
                      + red[2][threadIdx.x] + red[3][threadIdx.x];
        atomicAdd(&pooled[b * DD + threadIdx.x], v);
    }
}

// ---------------------------------------------------------------------------
// Latent head
// ---------------------------------------------------------------------------
__global__ __launch_bounds__(256) void head_kernel(
    const float* __restrict__ pooled,
    const float* __restrict__ lw1, const float* __restrict__ lb1,
    const float* __restrict__ lw2, const float* __restrict__ lb2,
    float* __restrict__ out)
{
    const int b = blockIdx.x;
    const int j = threadIdx.x;
    __shared__ float p[128];
    __shared__ float t1[256];
    if (j < 128) p[j] = pooled[b*DD + j] * (1.0f / (float)SS);
    __syncthreads();
    float acc = lb1[j];
    for (int k = 0; k < 128; ++k) acc = __builtin_fmaf(p[k], lw1[k * 256 + j], acc);
    t1[j] = gelu_fast(acc);
    __syncthreads();
    float acc2 = lb2[j];
    for (int k = 0; k < 256; ++k) acc2 = __builtin_fmaf(t1[k], lw2[k * 256 + j], acc2);
    out[b*DLL + j] = acc2;
}

extern "C" void kernel_launch(void* const* d_in, const int* in_sizes, int n_in,
                              void* d_out, int out_size, void* d_ws, size_t ws_size,
                              hipStream_t stream) {
    const int*   a0       = (const int*)d_in[0];
    const int*   a1       = (const int*)d_in[1];
    const int*   pidx     = (const int*)d_in[2];
    const float* bidir    = (const float*)d_in[3];
    const float* pos_emb  = (const float*)d_in[4];
    const float* pred_emb = (const float*)d_in[5];
    const float* w1       = (const float*)d_in[6];
    const float* b1       = (const float*)d_in[7];
    const float* w2       = (const float*)d_in[8];
    const float* b2       = (const float*)d_in[9];
    const float* ln_g     = (const float*)d_in[10];
    const float* ln_b     = (const float*)d_in[11];
    const float* lw1      = (const float*)d_in[12];
    const float* lb1      = (const float*)d_in[13];
    const float* lw2      = (const float*)d_in[14];
    const float* lb2      = (const float*)d_in[15];

    char* ws = (char*)d_ws;
    const size_t O_MSG  = 0;                               // 16 MB
    const size_t O_CNT  = 16777216;                        // 32 KB
    const size_t O_POOL = O_CNT + 32768;                   // 4 KB
    const size_t O_IDX  = O_POOL + 4096;                   // 576 KB
    const size_t O_W2P  = O_IDX + (size_t)NNODE * CAP * 2; // 64 KB
    const size_t O_PA   = O_W2P + 65536;                   // 512 KB
    const size_t O_PC   = O_PA + 524288;                   // 512 KB
    const size_t O_PE   = O_PC + 524288;                   // 7 KB

    ushort* msgbuf = (ushort*)(ws + O_MSG);
    int*    cnt    = (int*)(ws + O_CNT);
    float*  pooled = (float*)(ws + O_POOL);
    ushort* idx16  = (ushort*)(ws + O_IDX);
    ushort* w2p    = (ushort*)(ws + O_W2P);
    ushort* Pa     = (ushort*)(ws + O_PA);
    ushort* Pc     = (ushort*)(ws + O_PC);
    ushort* PE     = (ushort*)(ws + O_PE);

    prep_kernel<<<PREP_GRID, 256, 0, stream>>>(
        pos_emb, pred_emb, w1, b1, w2, Pa, Pc, PE, w2p, cnt, pooled);
    msg_kernel<<<NF / FPB, 256, 0, stream>>>(a0, a1, pidx, bidir,
        Pa, Pc, PE, w2p, b2, msgbuf, cnt, idx16);
    reduce_kernel<<<NNODE / 4, 256, 0, stream>>>(
        pos_emb, msgbuf, cnt, idx16, ln_g, ln_b, pooled);
    head_kernel<<<BB, 256, 0, stream>>>(pooled, lw1, lb1, lw2, lb2, (float*)d_out);
}

// Round 11
// 53.062 us; speedup vs baseline: 4.0994x; 1.2437x over previous
//
#include <hip/hip_runtime.h>
#include <hip/hip_bf16.h>

#define BB 8
#define FF 4096
#define SS 1024
#define DD 128
#define DLL 256
#define NF (BB*FF)     // 32768 facts
#define NMSG (2*NF)    // 65536 message slots
#define NNODE (BB*SS)  // 8192 (b,s) rows
#define CAP 36         // bucket capacity per node

typedef short  short8 __attribute__((ext_vector_type(8)));
typedef float  f32x4  __attribute__((ext_vector_type(4)));

__device__ __forceinline__ uint f2bf(float x) {
    uint u = __float_as_uint(x);
    return (u + 0x7fffu + ((u >> 16) & 1u)) >> 16;
}
__device__ __forceinline__ float bf2f(uint lo16) {
    return __uint_as_float(lo16 << 16);
}

// gelu(x) = 0.5x(1+erf(x/sqrt2)); erf via A&S 7.1.26, |err|<=1.5e-7, branchless.
__device__ __forceinline__ float gelu_fast(float x) {
    const float z = fabsf(x) * 0.70710678118654752440f;
    const float t = __builtin_amdgcn_rcpf(__builtin_fmaf(0.3275911f, z, 1.0f));
    float p = 1.061405429f;
    p = __builtin_fmaf(p, t, -1.453152027f);
    p = __builtin_fmaf(p, t, 1.421413741f);
    p = __builtin_fmaf(p, t, -0.284496736f);
    p = __builtin_fmaf(p, t, 0.254829592f);
    p *= t;
    const float e = __expf(-z * z);
    const float erfv = __builtin_fmaf(-p, e, 1.0f);
    return 0.5f * x * (1.0f + copysignf(erfv, x));
}

// ---------------------------------------------------------------------------
// Prep: table GEMMs Pa/Pc/PE (fp32 math, bf16 store), w2 frag-pack,
// bucket build (cnt pre-zeroed by memsetAsync).
//   Pa[s][j] = sum_k pos[s][k] w1[k][j]
//   Pc[s][j] = sum_k pos[s][k] w1[256+k][j]
//   PE[r][j] = sum_k pred[r][k] w1[128+k][j] + b1[j]
// ---------------------------------------------------------------------------
#define N_W2 (256*128)
#define PA_BLOCKS 256                      // 4 s-rows per block
#define PE_BLOCK  PA_BLOCKS
#define FLAT0     (PA_BLOCKS + 1)
#define N_FLAT    (N_W2 + NMSG)
#define FLAT_BLOCKS ((N_FLAT + 255) / 256)  // 384
#define PREP_GRID (FLAT0 + FLAT_BLOCKS)

__global__ __launch_bounds__(256) void prep_kernel(
    const float* __restrict__ pos_emb, const float* __restrict__ pred_emb,
    const float* __restrict__ w1, const float* __restrict__ b1,
    const float* __restrict__ w2,
    const int* __restrict__ a0, const int* __restrict__ a1,
    const float* __restrict__ bidir,
    ushort* __restrict__ Pa, ushort* __restrict__ Pc, ushort* __restrict__ PE,
    ushort* __restrict__ w2p, int* __restrict__ cnt, ushort* __restrict__ idx16)
{
    const int blk = blockIdx.x;
    const int tid = threadIdx.x;

    if (blk < PA_BLOCKS) {
        __shared__ float ps[4][128];
        const int s0 = blk * 4;
        for (int q = tid; q < 512; q += 256) ps[q >> 7][q & 127] = pos_emb[s0 * 128 + q];
        __syncthreads();
        const int j = tid;
        float aa[4], ac[4];
        #pragma unroll
        for (int r = 0; r < 4; ++r) { aa[r] = 0.0f; ac[r] = 0.0f; }
        #pragma unroll 4
        for (int k = 0; k < 128; ++k) {
            const float wa = w1[k * 256 + j];
            const float wc = w1[(256 + k) * 256 + j];
            #pragma unroll
            for (int r = 0; r < 4; ++r) {
                aa[r] = __builtin_fmaf(ps[r][k], wa, aa[r]);
                ac[r] = __builtin_fmaf(ps[r][k], wc, ac[r]);
            }
        }
        #pragma unroll
        for (int r = 0; r < 4; ++r) {
            Pa[(s0 + r) * 256 + j] = (ushort)f2bf(aa[r]);
            Pc[(s0 + r) * 256 + j] = (ushort)f2bf(ac[r]);
        }
        return;
    }
    if (blk == PE_BLOCK) {
        __shared__ float pr[14][128];
        for (int q = tid; q < 14 * 128; q += 256) pr[q >> 7][q & 127] = pred_emb[q];
        __syncthreads();
        const int j = tid;
        float acc[14];
        #pragma unroll
        for (int r = 0; r < 14; ++r) acc[r] = 0.0f;
        for (int k = 0; k < 128; ++k) {
            const float wb = w1[(128 + k) * 256 + j];
            #pragma unroll
            for (int r = 0; r < 14; ++r) acc[r] = __builtin_fmaf(pr[r][k], wb, acc[r]);
        }
        const float bj = b1[j];
        #pragma unroll
        for (int r = 0; r < 14; ++r) PE[r * 256 + j] = (ushort)f2bf(acc[r] + bj);
        return;
    }
    int i = (blk - FLAT0) * 256 + tid;
    if (i < N_W2) {   // i = k*128 + d -> frag-packed for GEMM2 A operand
        const int k = i >> 7, d = i & 127;
        const int d0 = d >> 4, lr = d & 15, ks = k >> 5, lq = (k >> 3) & 3, e = k & 7;
        w2p[(d0 * 8 + ks) * 512 + lr * 32 + lq * 8 + e] = (ushort)f2bf(w2[i]);
        return;
    }
    i -= N_W2;
    if (i < NMSG) {   // bucket build: msg slot i = fact*2 + parity
        const int g = i >> 1, p = i & 1;
        const float w = p ? bidir[g] : 1.0f;
        if (w != 0.0f) {
            const int nid = ((g >> 12) << 10) + (p ? a0[g] : a1[g]);
            const int slot = atomicAdd(&cnt[nid], 1);
            if (slot < CAP) idx16[nid * CAP + slot] = (ushort)i;
        }
    }
}

// ---------------------------------------------------------------------------
// node kernel: per 16-node tile — bucket-gather G = sum w*gelu(Pa[X]+PE[pi]
// +Pc[Y]) in fp32 regs -> bf16 swizzled LDS -> GEMM2 (node granularity) ->
// + wsum*b2 + pos_emb -> LayerNorm -> pooled.  512 blocks x 8 waves.
// ---------------------------------------------------------------------------
__global__ __launch_bounds__(512, 2) void node_kernel(
    const int* __restrict__ a0, const int* __restrict__ a1,
    const int* __restrict__ pidx, const float* __restrict__ bidir,
    const ushort* __restrict__ Pa, const ushort* __restrict__ Pc,
    const ushort* __restrict__ PE,
    const ushort* __restrict__ w2p, const float* __restrict__ b2,
    const float* __restrict__ pos_emb,
    const int* __restrict__ cnt, const ushort* __restrict__ idx16,
    const float* __restrict__ ln_g, const float* __restrict__ ln_b,
    float* __restrict__ pooled)
{
    __shared__ uint4 h1g[512];        // 16 rows x 512 B, swizzled (8 KB)
    __shared__ float wsumS[16];
    __shared__ float aggf[16][132];   // padded fp32 agg tile (8.4 KB)
    __shared__ float red[8][128];     // pooled partials (4 KB)

    const int tid = threadIdx.x;
    const int wid = tid >> 6, lane = tid & 63;
    const int lq = lane >> 4, lr = lane & 15;
    const int nbase = blockIdx.x * 16;

    // ---- phase 1: G accumulate per node (wave handles 2 nodes) ----
    #pragma unroll
    for (int i = 0; i < 2; ++i) {
        const int n = wid * 2 + i;           // local node 0..15
        const int nid = nbase + n;
        int c = cnt[nid]; if (c > CAP) c = CAP;
        const ushort* bucket = idx16 + nid * CAP;
        float G0 = 0.0f, G1 = 0.0f, G2 = 0.0f, G3 = 0.0f, ws = 0.0f;
        for (int j = 0; j < c; ++j) {
            const int mi = bucket[j];
            const int g = mi >> 1, p = mi & 1;
            const float w = p ? bidir[g] : 1.0f;
            const int ra0 = a0[g], ra1 = a1[g], rpi = pidx[g];
            const int X = p ? ra1 : ra0;
            const int Y = p ? ra0 : ra1;
            const uint2 ua = *(const uint2*)(Pa + X * 256 + lane * 4);
            const uint2 ub = *(const uint2*)(PE + rpi * 256 + lane * 4);
            const uint2 uc = *(const uint2*)(Pc + Y * 256 + lane * 4);
            const float h0 = bf2f(ua.x & 0xffffu) + bf2f(ub.x & 0xffffu) + bf2f(uc.x & 0xffffu);
            const float h1 = bf2f(ua.x >> 16)     + bf2f(ub.x >> 16)     + bf2f(uc.x >> 16);
            const float h2 = bf2f(ua.y & 0xffffu) + bf2f(ub.y & 0xffffu) + bf2f(uc.y & 0xffffu);
            const float h3 = bf2f(ua.y >> 16)     + bf2f(ub.y >> 16)     + bf2f(uc.y >> 16);
            G0 = __builtin_fmaf(w, gelu_fast(h0), G0);
            G1 = __builtin_fmaf(w, gelu_fast(h1), G1);
            G2 = __builtin_fmaf(w, gelu_fast(h2), G2);
            G3 = __builtin_fmaf(w, gelu_fast(h3), G3);
            ws += w;
        }
        uint2 t;
        t.x = f2bf(G0) | (f2bf(G1) << 16);
        t.y = f2bf(G2) | (f2bf(G3) << 16);
        const int col = lane * 8;     // byte col within 512B row
        const int byteoff = n * 512 + ((((col >> 4)) ^ (n & 15)) << 4) + (col & 15);
        *(uint2*)((char*)h1g + byteoff) = t;
        if (lane == 0) wsumS[n] = ws;
    }
    __syncthreads();

    // ---- GEMM2 (node granularity): D[d][m], m = lr, d = wid*16 + lq*4+r ----
    f32x4 acc = (f32x4)0.0f;
    #pragma unroll
    for (int ks = 0; ks < 8; ++ks) {
        const int m = lr;
        const short8 hfrag = *(const short8*)((char*)h1g + m * 512 + ((((ks * 4 + lq)) ^ (m & 15)) << 4));
        const short8 wfrag = *(const short8*)(w2p + (wid * 8 + ks) * 512 + lr * 32 + lq * 8);
        acc = __builtin_amdgcn_mfma_f32_16x16x32_bf16(wfrag, hfrag, acc, 0, 0, 0);
    }

    // ---- epilogue: + wsum*b2 + pos_emb -> aggf LDS ----
    {
        const float wsm = wsumS[lr];
        const int s = (nbase + lr) & (SS - 1);
        const int d0 = wid * 16 + lq * 4;
        const float4 b24 = *(const float4*)(b2 + d0);
        const float4 pe4 = *(const float4*)(pos_emb + s * DD + d0);
        float4 o;
        o.x = __builtin_fmaf(wsm, b24.x, acc[0] + pe4.x);
        o.y = __builtin_fmaf(wsm, b24.y, acc[1] + pe4.y);
        o.z = __builtin_fmaf(wsm, b24.z, acc[2] + pe4.z);
        o.w = __builtin_fmaf(wsm, b24.w, acc[3] + pe4.w);
        *(float4*)&aggf[lr][d0] = o;
    }
    __syncthreads();

    // ---- LayerNorm + pool: wave handles its 2 nodes ----
    const float g0 = ln_g[lane], g1 = ln_g[lane + 64];
    const float bb0 = ln_b[lane], bb1 = ln_b[lane + 64];
    float p0 = 0.0f, p1 = 0.0f;
    #pragma unroll
    for (int i = 0; i < 2; ++i) {
        const int n = wid * 2 + i;
        const float h0 = aggf[n][lane];
        const float h1 = aggf[n][lane + 64];
        float sum = h0 + h1;
        #pragma unroll
        for (int o = 32; o > 0; o >>= 1) sum += __shfl_xor(sum, o);
        const float mu = sum * (1.0f / 128.0f);
        const float d0 = h0 - mu, d1 = h1 - mu;
        float sq = d0 * d0 + d1 * d1;
        #pragma unroll
        for (int o = 32; o > 0; o >>= 1) sq += __shfl_xor(sq, o);
        const float rstd = rsqrtf(sq * (1.0f / 128.0f) + 1e-5f);
        p0 += d0 * rstd * g0 + bb0;
        p1 += d1 * rstd * g1 + bb1;
    }
    red[wid][lane]      = p0;
    red[wid][lane + 64] = p1;
    __syncthreads();
    if (tid < 128) {
        float v = 0.0f;
        #pragma unroll
        for (int w = 0; w < 8; ++w) v += red[w][tid];
        const int b = nbase >> 10;
        atomicAdd(&pooled[b * DD + tid], v);
    }
}

// ---------------------------------------------------------------------------
// Latent head
// ---------------------------------------------------------------------------
__global__ __launch_bounds__(256) void head_kernel(
    const float* __restrict__ pooled,
    const float* __restrict__ lw1, const float* __restrict__ lb1,
    const float* __restrict__ lw2, const float* __restrict__ lb2,
    float* __restrict__ out)
{
    const int b = blockIdx.x;
    const int j = threadIdx.x;
    __shared__ float p[128];
    __shared__ float t1[256];
    if (j < 128) p[j] = pooled[b*DD + j] * (1.0f / (float)SS);
    __syncthreads();
    float acc = lb1[j];
    for (int k = 0; k < 128; ++k) acc = __builtin_fmaf(p[k], lw1[k * 256 + j], acc);
    t1[j] = gelu_fast(acc);
    __syncthreads();
    float acc2 = lb2[j];
    for (int k = 0; k < 256; ++k) acc2 = __builtin_fmaf(t1[k], lw2[k * 256 + j], acc2);
    out[b*DLL + j] = acc2;
}

extern "C" void kernel_launch(void* const* d_in, const int* in_sizes, int n_in,
                              void* d_out, int out_size, void* d_ws, size_t ws_size,
                              hipStream_t stream) {
    const int*   a0       = (const int*)d_in[0];
    const int*   a1       = (const int*)d_in[1];
    const int*   pidx     = (const int*)d_in[2];
    const float* bidir    = (const float*)d_in[3];
    const float* pos_emb  = (const float*)d_in[4];
    const float* pred_emb = (const float*)d_in[5];
    const float* w1       = (const float*)d_in[6];
    const float* b1       = (const float*)d_in[7];
    const float* w2       = (const float*)d_in[8];
    const float* b2       = (const float*)d_in[9];
    const float* ln_g     = (const float*)d_in[10];
    const float* ln_b     = (const float*)d_in[11];
    const float* lw1      = (const float*)d_in[12];
    const float* lb1      = (const float*)d_in[13];
    const float* lw2      = (const float*)d_in[14];
    const float* lb2      = (const float*)d_in[15];

    char* ws = (char*)d_ws;
    const size_t O_CNT  = 0;                               // 32 KB (int[NNODE])
    const size_t O_POOL = 32768;                           // 4 KB  (fp32[B*D])
    const size_t O_IDX  = O_POOL + 4096;                   // 576 KB (NNODE*CAP u16)
    const size_t O_W2P  = O_IDX + (size_t)NNODE * CAP * 2; // 64 KB
    const size_t O_PA   = O_W2P + 65536;                   // 512 KB
    const size_t O_PC   = O_PA + 524288;                   // 512 KB
    const size_t O_PE   = O_PC + 524288;                   // 7 KB

    int*    cnt    = (int*)(ws + O_CNT);
    float*  pooled = (float*)(ws + O_POOL);
    ushort* idx16  = (ushort*)(ws + O_IDX);
    ushort* w2p    = (ushort*)(ws + O_W2P);
    ushort* Pa     = (ushort*)(ws + O_PA);
    ushort* Pc     = (ushort*)(ws + O_PC);
    ushort* PE     = (ushort*)(ws + O_PE);

    hipMemsetAsync(ws, 0, 32768 + 4096, stream);   // cnt + pooled
    prep_kernel<<<PREP_GRID, 256, 0, stream>>>(
        pos_emb, pred_emb, w1, b1, w2, a0, a1, bidir,
        Pa, Pc, PE, w2p, cnt, idx16);
    node_kernel<<<NNODE / 16, 512, 0, stream>>>(
        a0, a1, pidx, bidir, Pa, Pc, PE, w2p, b2, pos_emb,
        cnt, idx16, ln_g, ln_b, pooled);
    head_kernel<<<BB, 256, 0, stream>>>(pooled, lw1, lb1, lw2, lb2, (float*)d_out);
}

// Round 12
// 51.217 us; speedup vs baseline: 4.2471x; 1.0360x over previous
//
#include <hip/hip_runtime.h>
#include <hip/hip_bf16.h>

#define BB 8
#define FF 4096
#define SS 1024
#define DD 128
#define DLL 256
#define NF (BB*FF)     // 32768 facts
#define NMSG (2*NF)    // 65536 message slots
#define NNODE (BB*SS)  // 8192 (b,s) rows
#define CAP 36         // bucket capacity per node

typedef short  short8 __attribute__((ext_vector_type(8)));
typedef float  f32x4  __attribute__((ext_vector_type(4)));

__device__ __forceinline__ uint f2bf(float x) {
    uint u = __float_as_uint(x);
    return (u + 0x7fffu + ((u >> 16) & 1u)) >> 16;
}
__device__ __forceinline__ float bf2f(uint lo16) {
    return __uint_as_float(lo16 << 16);
}

// gelu(x) = 0.5x(1+erf(x/sqrt2)); erf via A&S 7.1.26, |err|<=1.5e-7, branchless.
__device__ __forceinline__ float gelu_fast(float x) {
    const float z = fabsf(x) * 0.70710678118654752440f;
    const float t = __builtin_amdgcn_rcpf(__builtin_fmaf(0.3275911f, z, 1.0f));
    float p = 1.061405429f;
    p = __builtin_fmaf(p, t, -1.453152027f);
    p = __builtin_fmaf(p, t, 1.421413741f);
    p = __builtin_fmaf(p, t, -0.284496736f);
    p = __builtin_fmaf(p, t, 0.254829592f);
    p *= t;
    const float e = __expf(-z * z);
    const float erfv = __builtin_fmaf(-p, e, 1.0f);
    return 0.5f * x * (1.0f + copysignf(erfv, x));
}

// ---------------------------------------------------------------------------
// Zero kernel: cnt[NNODE] + pooled[BB*DD]  (replaces pathological memset fill)
// ---------------------------------------------------------------------------
__global__ __launch_bounds__(256) void zero_kernel(int* __restrict__ cnt,
                                                   float* __restrict__ pooled)
{
    const int i = blockIdx.x * 256 + threadIdx.x;
    if (i < NNODE) { cnt[i] = 0; return; }
    const int j = i - NNODE;
    if (j < BB * DD) pooled[j] = 0.0f;
}

// ---------------------------------------------------------------------------
// Prep: table GEMMs Pa/Pc/PE (fp32 math, bf16 store), w2 frag-pack,
// packed bucket build.
//   Pa[s][j] = sum_k pos[s][k] w1[k][j]
//   Pc[s][j] = sum_k pos[s][k] w1[256+k][j]
//   PE[r][j] = sum_k pred[r][k] w1[128+k][j] + b1[j]
// Bucket entry = X | Y<<10 | rpi<<20  (all active messages have weight 1).
// ---------------------------------------------------------------------------
#define N_W2 (256*128)
#define PA_BLOCKS 256                      // 4 s-rows per block
#define PE_BLOCK  PA_BLOCKS
#define FLAT0     (PA_BLOCKS + 1)
#define N_FLAT    (N_W2 + NMSG)
#define FLAT_BLOCKS ((N_FLAT + 255) / 256)  // 384
#define PREP_GRID (FLAT0 + FLAT_BLOCKS)

__global__ __launch_bounds__(256) void prep_kernel(
    const float* __restrict__ pos_emb, const float* __restrict__ pred_emb,
    const float* __restrict__ w1, const float* __restrict__ b1,
    const float* __restrict__ w2,
    const int* __restrict__ a0, const int* __restrict__ a1,
    const int* __restrict__ pidx, const float* __restrict__ bidir,
    ushort* __restrict__ Pa, ushort* __restrict__ Pc, ushort* __restrict__ PE,
    ushort* __restrict__ w2p, int* __restrict__ cnt, uint* __restrict__ idx32)
{
    const int blk = blockIdx.x;
    const int tid = threadIdx.x;

    if (blk < PA_BLOCKS) {
        __shared__ float ps[4][128];
        const int s0 = blk * 4;
        for (int q = tid; q < 512; q += 256) ps[q >> 7][q & 127] = pos_emb[s0 * 128 + q];
        __syncthreads();
        const int j = tid;
        float aa[4], ac[4];
        #pragma unroll
        for (int r = 0; r < 4; ++r) { aa[r] = 0.0f; ac[r] = 0.0f; }
        #pragma unroll 4
        for (int k = 0; k < 128; ++k) {
            const float wa = w1[k * 256 + j];
            const float wc = w1[(256 + k) * 256 + j];
            #pragma unroll
            for (int r = 0; r < 4; ++r) {
                aa[r] = __builtin_fmaf(ps[r][k], wa, aa[r]);
                ac[r] = __builtin_fmaf(ps[r][k], wc, ac[r]);
            }
        }
        #pragma unroll
        for (int r = 0; r < 4; ++r) {
            Pa[(s0 + r) * 256 + j] = (ushort)f2bf(aa[r]);
            Pc[(s0 + r) * 256 + j] = (ushort)f2bf(ac[r]);
        }
        return;
    }
    if (blk == PE_BLOCK) {
        __shared__ float pr[14][128];
        for (int q = tid; q < 14 * 128; q += 256) pr[q >> 7][q & 127] = pred_emb[q];
        __syncthreads();
        const int j = tid;
        float acc[14];
        #pragma unroll
        for (int r = 0; r < 14; ++r) acc[r] = 0.0f;
        for (int k = 0; k < 128; ++k) {
            const float wb = w1[(128 + k) * 256 + j];
            #pragma unroll
            for (int r = 0; r < 14; ++r) acc[r] = __builtin_fmaf(pr[r][k], wb, acc[r]);
        }
        const float bj = b1[j];
        #pragma unroll
        for (int r = 0; r < 14; ++r) PE[r * 256 + j] = (ushort)f2bf(acc[r] + bj);
        return;
    }
    int i = (blk - FLAT0) * 256 + tid;
    if (i < N_W2) {   // i = k*128 + d -> frag-packed for GEMM2 A operand
        const int k = i >> 7, d = i & 127;
        const int d0 = d >> 4, lr = d & 15, ks = k >> 5, lq = (k >> 3) & 3, e = k & 7;
        w2p[(d0 * 8 + ks) * 512 + lr * 32 + lq * 8 + e] = (ushort)f2bf(w2[i]);
        return;
    }
    i -= N_W2;
    if (i < NMSG) {   // packed bucket build: msg slot i = fact*2 + parity
        const int g = i >> 1, p = i & 1;
        const float w = p ? bidir[g] : 1.0f;
        if (w != 0.0f) {
            const int ra0 = a0[g], ra1 = a1[g];
            const int X = p ? ra1 : ra0;       // through W1a
            const int Y = p ? ra0 : ra1;       // through W1c
            const int dest = p ? ra0 : ra1;    // destination node
            const int nid = ((g >> 12) << 10) + dest;
            const int slot = atomicAdd(&cnt[nid], 1);
            if (slot < CAP)
                idx32[nid * CAP + slot] = (uint)X | ((uint)Y << 10) | ((uint)pidx[g] << 20);
        }
    }
}

// ---------------------------------------------------------------------------
// node kernel: per 16-node tile — bucket-gather G = sum gelu(Pa[X]+PE[pi]
// +Pc[Y]) in fp32 regs -> bf16 swizzled LDS -> GEMM2 (node granularity) ->
// + c*b2 + pos_emb -> LayerNorm -> pooled.  512 blocks x 8 waves.
// ---------------------------------------------------------------------------
__global__ __launch_bounds__(512, 2) void node_kernel(
    const ushort* __restrict__ Pa, const ushort* __restrict__ Pc,
    const ushort* __restrict__ PE,
    const ushort* __restrict__ w2p, const float* __restrict__ b2,
    const float* __restrict__ pos_emb,
    const int* __restrict__ cnt, const uint* __restrict__ idx32,
    const float* __restrict__ ln_g, const float* __restrict__ ln_b,
    float* __restrict__ pooled)
{
    __shared__ uint4 h1g[512];        // 16 rows x 512 B, swizzled (8 KB)
    __shared__ float wsumS[16];
    __shared__ float aggf[16][132];   // padded fp32 agg tile (8.4 KB)
    __shared__ float red[8][128];     // pooled partials (4 KB)

    const int tid = threadIdx.x;
    const int wid = tid >> 6, lane = tid & 63;
    const int lq = lane >> 4, lr = lane & 15;
    const int nbase = blockIdx.x * 16;

    // ---- phase 1: G accumulate per node (wave handles 2 nodes) ----
    #pragma unroll
    for (int i = 0; i < 2; ++i) {
        const int n = wid * 2 + i;           // local node 0..15
        const int nid = nbase + n;
        int c = cnt[nid]; if (c > CAP) c = CAP;
        const uint* bucket = idx32 + nid * CAP;
        float G0 = 0.0f, G1 = 0.0f, G2 = 0.0f, G3 = 0.0f;
        for (int j = 0; j < c; ++j) {
            const uint e = bucket[j];
            const int X = e & 1023;
            const int Y = (e >> 10) & 1023;
            const int rpi = e >> 20;
            const uint2 ua = *(const uint2*)(Pa + X * 256 + lane * 4);
            const uint2 ub = *(const uint2*)(PE + rpi * 256 + lane * 4);
            const uint2 uc = *(const uint2*)(Pc + Y * 256 + lane * 4);
            const float h0 = bf2f(ua.x & 0xffffu) + bf2f(ub.x & 0xffffu) + bf2f(uc.x & 0xffffu);
            const float h1 = bf2f(ua.x >> 16)     + bf2f(ub.x >> 16)     + bf2f(uc.x >> 16);
            const float h2 = bf2f(ua.y & 0xffffu) + bf2f(ub.y & 0xffffu) + bf2f(uc.y & 0xffffu);
            const float h3 = bf2f(ua.y >> 16)     + bf2f(ub.y >> 16)     + bf2f(uc.y >> 16);
            G0 += gelu_fast(h0);
            G1 += gelu_fast(h1);
            G2 += gelu_fast(h2);
            G3 += gelu_fast(h3);
        }
        uint2 t;
        t.x = f2bf(G0) | (f2bf(G1) << 16);
        t.y = f2bf(G2) | (f2bf(G3) << 16);
        const int col = lane * 8;     // byte col within 512B row
        const int byteoff = n * 512 + ((((col >> 4)) ^ (n & 15)) << 4) + (col & 15);
        *(uint2*)((char*)h1g + byteoff) = t;
        if (lane == 0) wsumS[n] = (float)c;
    }
    __syncthreads();

    // ---- GEMM2 (node granularity): D[d][m], m = lr, d = wid*16 + lq*4+r ----
    f32x4 acc = (f32x4)0.0f;
    #pragma unroll
    for (int ks = 0; ks < 8; ++ks) {
        const int m = lr;
        const short8 hfrag = *(const short8*)((char*)h1g + m * 512 + ((((ks * 4 + lq)) ^ (m & 15)) << 4));
        const short8 wfrag = *(const short8*)(w2p + (wid * 8 + ks) * 512 + lr * 32 + lq * 8);
        acc = __builtin_amdgcn_mfma_f32_16x16x32_bf16(wfrag, hfrag, acc, 0, 0, 0);
    }

    // ---- epilogue: + wsum*b2 + pos_emb -> aggf LDS ----
    {
        const float wsm = wsumS[lr];
        const int s = (nbase + lr) & (SS - 1);
        const int d0 = wid * 16 + lq * 4;
        const float4 b24 = *(const float4*)(b2 + d0);
        const float4 pe4 = *(const float4*)(pos_emb + s * DD + d0);
        float4 o;
        o.x = __builtin_fmaf(wsm, b24.x, acc[0] + pe4.x);
        o.y = __builtin_fmaf(wsm, b24.y, acc[1] + pe4.y);
        o.z = __builtin_fmaf(wsm, b24.z, acc[2] + pe4.z);
        o.w = __builtin_fmaf(wsm, b24.w, acc[3] + pe4.w);
        *(float4*)&aggf[lr][d0] = o;
    }
    __syncthreads();

    // ---- LayerNorm + pool: wave handles its 2 nodes ----
    const float g0 = ln_g[lane], g1 = ln_g[lane + 64];
    const float bb0 = ln_b[lane], bb1 = ln_b[lane + 64];
    float p0 = 0.0f, p1 = 0.0f;
    #pragma unroll
    for (int i = 0; i < 2; ++i) {
        const int n = wid * 2 + i;
        const float h0 = aggf[n][lane];
        const float h1 = aggf[n][lane + 64];
        float sum = h0 + h1;
        #pragma unroll
        for (int o = 32; o > 0; o >>= 1) sum += __shfl_xor(sum, o);
        const float mu = sum * (1.0f / 128.0f);
        const float d0 = h0 - mu, d1 = h1 - mu;
        float sq = d0 * d0 + d1 * d1;
        #pragma unroll
        for (int o = 32; o > 0; o >>= 1) sq += __shfl_xor(sq, o);
        const float rstd = rsqrtf(sq * (1.0f / 128.0f) + 1e-5f);
        p0 += d0 * rstd * g0 + bb0;
        p1 += d1 * rstd * g1 + bb1;
    }
    red[wid][lane]      = p0;
    red[wid][lane + 64] = p1;
    __syncthreads();
    if (tid < 128) {
        float v = 0.0f;
        #pragma unroll
        for (int w = 0; w < 8; ++w) v += red[w][tid];
        const int b = nbase >> 10;
        atomicAdd(&pooled[b * DD + tid], v);
    }
}

// ---------------------------------------------------------------------------
// Latent head
// ---------------------------------------------------------------------------
__global__ __launch_bounds__(256) void head_kernel(
    const float* __restrict__ pooled,
    const float* __restrict__ lw1, const float* __restrict__ lb1,
    const float* __restrict__ lw2, const float* __restrict__ lb2,
    float* __restrict__ out)
{
    const int b = blockIdx.x;
    const int j = threadIdx.x;
    __shared__ float p[128];
    __shared__ float t1[256];
    if (j < 128) p[j] = pooled[b*DD + j] * (1.0f / (float)SS);
    __syncthreads();
    float acc = lb1[j];
    for (int k = 0; k < 128; ++k) acc = __builtin_fmaf(p[k], lw1[k * 256 + j], acc);
    t1[j] = gelu_fast(acc);
    __syncthreads();
    float acc2 = lb2[j];
    for (int k = 0; k < 256; ++k) acc2 = __builtin_fmaf(t1[k], lw2[k * 256 + j], acc2);
    out[b*DLL + j] = acc2;
}

extern "C" void kernel_launch(void* const* d_in, const int* in_sizes, int n_in,
                              void* d_out, int out_size, void* d_ws, size_t ws_size,
                              hipStream_t stream) {
    const int*   a0       = (const int*)d_in[0];
    const int*   a1       = (const int*)d_in[1];
    const int*   pidx     = (const int*)d_in[2];
    const float* bidir    = (const float*)d_in[3];
    const float* pos_emb  = (const float*)d_in[4];
    const float* pred_emb = (const float*)d_in[5];
    const float* w1       = (const float*)d_in[6];
    const float* b1       = (const float*)d_in[7];
    const float* w2       = (const float*)d_in[8];
    const float* b2       = (const float*)d_in[9];
    const float* ln_g     = (const float*)d_in[10];
    const float* ln_b     = (const float*)d_in[11];
    const float* lw1      = (const float*)d_in[12];
    const float* lb1      = (const float*)d_in[13];
    const float* lw2      = (const float*)d_in[14];
    const float* lb2      = (const float*)d_in[15];

    char* ws = (char*)d_ws;
    const size_t O_CNT  = 0;                                // 32 KB (int[NNODE])
    const size_t O_POOL = 32768;                            // 4 KB  (fp32[B*D])
    const size_t O_IDX  = O_POOL + 4096;                    // 1.18 MB (NNODE*CAP u32)
    const size_t O_W2P  = O_IDX + (size_t)NNODE * CAP * 4;  // 64 KB
    const size_t O_PA   = O_W2P + 65536;                    // 512 KB
    const size_t O_PC   = O_PA + 524288;                    // 512 KB
    const size_t O_PE   = O_PC + 524288;                    // 7 KB

    int*    cnt    = (int*)(ws + O_CNT);
    float*  pooled = (float*)(ws + O_POOL);
    uint*   idx32  = (uint*)(ws + O_IDX);
    ushort* w2p    = (ushort*)(ws + O_W2P);
    ushort* Pa     = (ushort*)(ws + O_PA);
    ushort* Pc     = (ushort*)(ws + O_PC);
    ushort* PE     = (ushort*)(ws + O_PE);

    zero_kernel<<<(NNODE + BB*DD + 255) / 256, 256, 0, stream>>>(cnt, pooled);
    prep_kernel<<<PREP_GRID, 256, 0, stream>>>(
        pos_emb, pred_emb, w1, b1, w2, a0, a1, pidx, bidir,
        Pa, Pc, PE, w2p, cnt, idx32);
    node_kernel<<<NNODE / 16, 512, 0, stream>>>(
        Pa, Pc, PE, w2p, b2, pos_emb, cnt, idx32, ln_g, ln_b, pooled);
    head_kernel<<<BB, 256, 0, stream>>>(pooled, lw1, lb1, lw2, lb2, (float*)d_out);
}